// Round 17
// baseline (375.301 us; speedup 1.0000x reference)
//
#include <hip/hip_runtime.h>

typedef float f32x4 __attribute__((ext_vector_type(4)));
typedef __bf16 bf16x8 __attribute__((ext_vector_type(8)));
typedef unsigned short u16x8 __attribute__((ext_vector_type(8)));

__device__ __forceinline__ unsigned short f2bf(float f) {
  union { float f; unsigned int u; } v; v.f = f;
  unsigned int u = v.u;
  unsigned int r = (u + 0x7FFFu + ((u >> 16) & 1u)) >> 16;  // RNE
  return (unsigned short)r;
}

// ------------- cast x (f32 -> bf16), 8 elems/thread, one-shot grid -------------
__global__ __launch_bounds__(256) void k_cast_bf16(const float* __restrict__ in,
                                                   unsigned short* __restrict__ out, int n8) {
  int i = blockIdx.x * 256 + threadIdx.x;
  if (i >= n8) return;
  const f32x4* p = (const f32x4*)in;
  f32x4 a = p[2 * i], b = p[2 * i + 1];
  u16x8 o;
  o[0] = f2bf(a[0]); o[1] = f2bf(a[1]); o[2] = f2bf(a[2]); o[3] = f2bf(a[3]);
  o[4] = f2bf(b[0]); o[5] = f2bf(b[1]); o[6] = f2bf(b[2]); o[7] = f2bf(b[3]);
  ((u16x8*)out)[i] = o;
}

// ---- fused: Bw[o][e*16+r] = w[e]*Bf[e][o][r]  AND  At[d][e*16+r] = A[e][r][d] ----
__global__ void k_build_bwat(const float* __restrict__ Bf,
                             const float* __restrict__ coeffs,
                             const float* __restrict__ scales,
                             const float* __restrict__ A,
                             unsigned short* __restrict__ bw,
                             unsigned short* __restrict__ at) {
  __shared__ float tile[64][65];
  if (blockIdx.x < 4096) {
    int t = blockIdx.x * 256 + threadIdx.x;
    int o = t >> 8, k = t & 255, e = k >> 4, r = k & 15;
    float v = coeffs[e] * scales[e] * Bf[((size_t)e * 4096 + o) * 16 + r];
    bw[t] = f2bf(v);
  } else {
    int b = blockIdx.x - 4096;
    int kt = (b & 3) * 64, dt = (b >> 2) * 64;
    int tx = threadIdx.x & 63, ty = threadIdx.x >> 6;
#pragma unroll
    for (int j = 0; j < 64; j += 4)
      tile[ty + j][tx] = A[(size_t)(kt + ty + j) * 4096 + dt + tx];
    __syncthreads();
#pragma unroll
    for (int j = 0; j < 64; j += 4)
      at[(size_t)(dt + ty + j) * 256 + kt + tx] = f2bf(tile[tx][ty + j]);
  }
}

// ------------- prep GEMM (m97 structure), W_eff = Bw @ At^T + W -------------
template <int M_, int N_, int K_>
__global__ __launch_bounds__(256) void k_gemm_prep(
    const unsigned short* __restrict__ Abuf,
    const unsigned short* __restrict__ Bbuf,
    const float* __restrict__ Wadd,
    unsigned short* __restrict__ outB) {
  constexpr int NBN = N_ / 128;
  constexpr int NWG = (M_ / 128) * NBN;
  const int bid = blockIdx.x;
  const int swz = (bid & 7) * (NWG / 8) + (bid >> 3);
  const int bm = swz / NBN, bn = swz % NBN;

  __shared__ unsigned short ldsA[128 * 64];
  __shared__ unsigned short ldsB[128 * 64];

  const int t = threadIdx.x, w = t >> 6, l = t & 63;
  const int wr = w >> 1, wc = w & 1;

  f32x4 acc[4][4] = {};
  const int m0 = bm * 128, n0 = bn * 128;
  const int srow = w * 8 + (l >> 3);
  const int scol = (l & 7) * 8;
  const unsigned short* gA = Abuf + (size_t)(m0 + srow) * K_ + scol;
  const unsigned short* gB = Bbuf + (size_t)(n0 + srow) * K_ + scol;

  for (int kt = 0; kt < K_; kt += 64) {
#pragma unroll
    for (int i = 0; i < 4; ++i) {
      __builtin_amdgcn_global_load_lds(
          (__attribute__((address_space(1))) void*)(gA + (size_t)i * 32 * K_ + kt),
          (__attribute__((address_space(3))) void*)(ldsA + i * 2048 + w * 512), 16, 0, 0);
      __builtin_amdgcn_global_load_lds(
          (__attribute__((address_space(1))) void*)(gB + (size_t)i * 32 * K_ + kt),
          (__attribute__((address_space(3))) void*)(ldsB + i * 2048 + w * 512), 16, 0, 0);
    }
    __syncthreads();
#pragma unroll
    for (int kk = 0; kk < 2; ++kk) {
      const int col = kk * 32 + (l >> 4) * 8;
      const int arow = wr * 64 + (l & 15);
      const int brow = wc * 64 + (l & 15);
      bf16x8 af[4], bfv[4];
#pragma unroll
      for (int mi = 0; mi < 4; ++mi)
        af[mi] = *(const bf16x8*)&ldsA[(arow + mi * 16) * 64 + col];
#pragma unroll
      for (int ni = 0; ni < 4; ++ni)
        bfv[ni] = *(const bf16x8*)&ldsB[(brow + ni * 16) * 64 + col];
#pragma unroll
      for (int mi = 0; mi < 4; ++mi)
#pragma unroll
        for (int ni = 0; ni < 4; ++ni)
          acc[mi][ni] = __builtin_amdgcn_mfma_f32_16x16x32_bf16(
              af[mi], bfv[ni], acc[mi][ni], 0, 0, 0);
    }
    __syncthreads();
  }

  const int mrow0 = m0 + wr * 64 + (l >> 4) * 4;
  const int ncol0 = n0 + wc * 64 + (l & 15);
#pragma unroll
  for (int mi = 0; mi < 4; ++mi)
#pragma unroll
    for (int r = 0; r < 4; ++r) {
      const int m = mrow0 + mi * 16 + r;
#pragma unroll
      for (int ni = 0; ni < 4; ++ni) {
        const int n = ncol0 + ni * 16;
        outB[(size_t)m * N_ + n] = f2bf(acc[mi][ni][r] + Wadd[(size_t)m * N_ + n]);
      }
    }
}

// ===== main GEMM: R6 ring-5 skeleton + DOUBLE-BARRIER phases (m201 mechanism) =====
// Per phase: {ds_reads + [stage] -> BARRIER -> lgkmcnt(0)+SB -> setprio 16 MFMA
// -> BARRIER}.  Pre-MFMA barrier aligns issue; each wave then waits only its
// OWN reads, so MFMA starts staggered across waves while the LDS queue drains
// under the MFMA bursts (overlap).  The POST-MFMA barrier bounds the drift so
// the stagger repeats instead of compounding -- the piece R15 omitted (its
// drift compounded into the iter-top convergence).  Stage placement + vmcnt
// identical to R6 (proven); buffer liveness unchanged.
template <int M_, int N_, int K_>
__global__ __launch_bounds__(512, 2) void k_gemm256(
    const unsigned short* __restrict__ Abuf,
    const unsigned short* __restrict__ Bbuf,
    const float* __restrict__ bias,
    float* __restrict__ outF) {
  constexpr int NBN = N_ / 256;
  constexpr int NWG = (M_ / 256) * NBN;
  constexpr int NT = K_ / 32;
  static_assert(NWG % 8 == 0, "bijective xcd swizzle");
  static_assert(NT % 2 == 0 && NT >= 6, "pipeline depth");

  const int bid = blockIdx.x;
  const int swz = (bid & 7) * (NWG / 8) + (bid >> 3);
  const int bm = swz / NBN, bn = swz % NBN;
  const int m0 = bm * 256, n0 = bn * 256;

  __shared__ __attribute__((aligned(128))) unsigned short lds[81920];  // 160 KiB
  char* ldsb = (char*)lds;

  const int tid = threadIdx.x, w = tid >> 6, l = tid & 63;
  const int wr = w >> 2, wc = w & 3;  // 2 M-waves x 4 N-waves; per-wave 128x64

  const int scol = ((l & 3) ^ ((l >> 3) & 3)) * 8;
  const unsigned short* gA = Abuf + (size_t)(m0 + w * 16 + (l >> 2)) * K_ + scol;
  const unsigned short* gB = Bbuf + (size_t)(n0 + w * 16 + (l >> 2)) * K_ + scol;
  const int dA = w * 1024;            // + buf*32768 + i*8192
  const int dB = 16384 + w * 1024;

  const int qp = ((l >> 4) ^ ((l >> 1) & 3)) << 4;
  const int raOff = (wr * 128 + (l & 15)) * 64 + qp;           // + mi*1024
  const int rbOff = 16384 + (wc * 64 + (l & 15)) * 64 + qp;    // + ni*1024

  f32x4 acc[8][4] = {};

#define STAGE_T(tt, bf)                                                               \
  do {                                                                                \
    const int bb_ = (bf) * 32768;                                                     \
    const size_t ko_ = (size_t)(tt) * 32;                                             \
    _Pragma("unroll") for (int i_ = 0; i_ < 2; ++i_) {                                \
      __builtin_amdgcn_global_load_lds(                                               \
          (__attribute__((address_space(1))) void*)(gA + (size_t)i_ * 128 * K_ + ko_),\
          (__attribute__((address_space(3))) void*)(ldsb + bb_ + i_ * 8192 + dA),     \
          16, 0, 0);                                                                  \
      __builtin_amdgcn_global_load_lds(                                               \
          (__attribute__((address_space(1))) void*)(gB + (size_t)i_ * 128 * K_ + ko_),\
          (__attribute__((address_space(3))) void*)(ldsb + bb_ + i_ * 8192 + dB),     \
          16, 0, 0);                                                                  \
    }                                                                                 \
  } while (0)

#define RD_A(mi, bf) (*(const bf16x8*)(ldsb + (bf) * 32768 + raOff + (mi) * 1024))
#define RD_B(ni, bf) (*(const bf16x8*)(ldsb + (bf) * 32768 + rbOff + (ni) * 1024))
#define SB __builtin_amdgcn_sched_barrier(0)
// gate between issued reads and their MFMA consumer cluster (rule #18)
#define GATE                                                                          \
  do {                                                                                \
    SB;                                                                               \
    __builtin_amdgcn_s_barrier();                                                     \
    asm volatile("s_waitcnt lgkmcnt(0)" ::: "memory");                                \
    SB;                                                                               \
  } while (0)

  // prologue: stage tiles 0,1,2 into bufs 0,1,2 (12 loads in flight)
  STAGE_T(0, 0); STAGE_T(1, 1); STAGE_T(2, 2);

  int bT = 0;  // buf index of tile tt (tt % 5)
  for (int tt = 0; tt < NT; tt += 2) {
    const int b0 = bT;
    const int b1 = (bT + 1 >= 5) ? bT + 1 - 5 : bT + 1;
    const int s3 = (bT + 3 >= 5) ? bT + 3 - 5 : bT + 3;
    const int s4 = (bT + 4 >= 5) ? bT + 4 - 5 : bT + 4;

    // iter top: prove tiles tt, tt+1 landed (keep newest stages in flight)
    if (tt + 2 < NT) asm volatile("s_waitcnt vmcnt(4)" ::: "memory");
    else             asm volatile("s_waitcnt vmcnt(0)" ::: "memory");
    __builtin_amdgcn_s_barrier();
    SB;

    // ---- phase 1: tile tt, mi0-3 ----
    bf16x8 a0 = RD_A(0, b0), a1 = RD_A(1, b0), a2 = RD_A(2, b0), a3 = RD_A(3, b0);
    bf16x8 v0 = RD_B(0, b0), v1 = RD_B(1, b0), v2 = RD_B(2, b0), v3 = RD_B(3, b0);
    if (tt + 3 < NT) STAGE_T(tt + 3, s3);
    GATE;
    __builtin_amdgcn_s_setprio(1);
#pragma unroll
    for (int ni = 0; ni < 4; ++ni) {
      bf16x8 vv = (ni == 0) ? v0 : (ni == 1) ? v1 : (ni == 2) ? v2 : v3;
      acc[0][ni] = __builtin_amdgcn_mfma_f32_16x16x32_bf16(a0, vv, acc[0][ni], 0, 0, 0);
      acc[1][ni] = __builtin_amdgcn_mfma_f32_16x16x32_bf16(a1, vv, acc[1][ni], 0, 0, 0);
      acc[2][ni] = __builtin_amdgcn_mfma_f32_16x16x32_bf16(a2, vv, acc[2][ni], 0, 0, 0);
      acc[3][ni] = __builtin_amdgcn_mfma_f32_16x16x32_bf16(a3, vv, acc[3][ni], 0, 0, 0);
    }
    __builtin_amdgcn_s_setprio(0);
    __builtin_amdgcn_s_barrier();          // bound drift

    // ---- phase 2: tile tt, mi4-7 (B regs reused) ----
    bf16x8 a4 = RD_A(4, b0), a5 = RD_A(5, b0), a6 = RD_A(6, b0), a7 = RD_A(7, b0);
    GATE;
    __builtin_amdgcn_s_setprio(1);
#pragma unroll
    for (int ni = 0; ni < 4; ++ni) {
      bf16x8 vv = (ni == 0) ? v0 : (ni == 1) ? v1 : (ni == 2) ? v2 : v3;
      acc[4][ni] = __builtin_amdgcn_mfma_f32_16x16x32_bf16(a4, vv, acc[4][ni], 0, 0, 0);
      acc[5][ni] = __builtin_amdgcn_mfma_f32_16x16x32_bf16(a5, vv, acc[5][ni], 0, 0, 0);
      acc[6][ni] = __builtin_amdgcn_mfma_f32_16x16x32_bf16(a6, vv, acc[6][ni], 0, 0, 0);
      acc[7][ni] = __builtin_amdgcn_mfma_f32_16x16x32_bf16(a7, vv, acc[7][ni], 0, 0, 0);
    }
    __builtin_amdgcn_s_setprio(0);
    __builtin_amdgcn_s_barrier();

    // ---- phase 3: tile tt+1, mi0-3 ----
    bf16x8 c0 = RD_A(0, b1), c1 = RD_A(1, b1), c2 = RD_A(2, b1), c3 = RD_A(3, b1);
    bf16x8 u0 = RD_B(0, b1), u1 = RD_B(1, b1), u2 = RD_B(2, b1), u3 = RD_B(3, b1);
    if (tt + 4 < NT) STAGE_T(tt + 4, s4);
    GATE;
    __builtin_amdgcn_s_setprio(1);
#pragma unroll
    for (int ni = 0; ni < 4; ++ni) {
      bf16x8 uu = (ni == 0) ? u0 : (ni == 1) ? u1 : (ni == 2) ? u2 : u3;
      acc[0][ni] = __builtin_amdgcn_mfma_f32_16x16x32_bf16(c0, uu, acc[0][ni], 0, 0, 0);
      acc[1][ni] = __builtin_amdgcn_mfma_f32_16x16x32_bf16(c1, uu, acc[1][ni], 0, 0, 0);
      acc[2][ni] = __builtin_amdgcn_mfma_f32_16x16x32_bf16(c2, uu, acc[2][ni], 0, 0, 0);
      acc[3][ni] = __builtin_amdgcn_mfma_f32_16x16x32_bf16(c3, uu, acc[3][ni], 0, 0, 0);
    }
    __builtin_amdgcn_s_setprio(0);
    __builtin_amdgcn_s_barrier();

    // ---- phase 4: tile tt+1, mi4-7 ----
    bf16x8 c4 = RD_A(4, b1), c5 = RD_A(5, b1), c6 = RD_A(6, b1), c7 = RD_A(7, b1);
    GATE;
    __builtin_amdgcn_s_setprio(1);
#pragma unroll
    for (int ni = 0; ni < 4; ++ni) {
      bf16x8 uu = (ni == 0) ? u0 : (ni == 1) ? u1 : (ni == 2) ? u2 : u3;
      acc[4][ni] = __builtin_amdgcn_mfma_f32_16x16x32_bf16(c4, uu, acc[4][ni], 0, 0, 0);
      acc[5][ni] = __builtin_amdgcn_mfma_f32_16x16x32_bf16(c5, uu, acc[5][ni], 0, 0, 0);
      acc[6][ni] = __builtin_amdgcn_mfma_f32_16x16x32_bf16(c6, uu, acc[6][ni], 0, 0, 0);
      acc[7][ni] = __builtin_amdgcn_mfma_f32_16x16x32_bf16(c7, uu, acc[7][ni], 0, 0, 0);
    }
    __builtin_amdgcn_s_setprio(0);
    __builtin_amdgcn_s_barrier();

    bT += 2; if (bT >= 5) bT -= 5;
  }
#undef STAGE_T
#undef RD_A
#undef RD_B
#undef SB
#undef GATE

  // epilogue: C/D layout col = lane&15, row = (lane>>4)*4 + reg
#pragma unroll
  for (int ni = 0; ni < 4; ++ni) {
    const int n = n0 + wc * 64 + ni * 16 + (l & 15);
    const float bv2 = bias[n];
#pragma unroll
    for (int mi = 0; mi < 8; ++mi) {
      const int m = m0 + wr * 128 + mi * 16 + (l >> 4) * 4;
#pragma unroll
      for (int r = 0; r < 4; ++r)
        outF[(size_t)(m + r) * N_ + n] = acc[mi][ni][r] + bv2;
    }
  }
}

extern "C" void kernel_launch(void* const* d_in, const int* in_sizes, int n_in,
                              void* d_out, int out_size, void* d_ws, size_t ws_size,
                              hipStream_t stream) {
  const float* x      = (const float*)d_in[0];
  const float* W      = (const float*)d_in[1];
  const float* bias   = (const float*)d_in[2];
  const float* A      = (const float*)d_in[3];
  const float* Bf     = (const float*)d_in[4];
  const float* coeffs = (const float*)d_in[5];
  const float* scales = (const float*)d_in[6];
  float* out = (float*)d_out;

  char* ws = (char*)d_ws;
  unsigned short* xb   = (unsigned short*)(ws);
  unsigned short* weff = (unsigned short*)(ws + 67108864);
  unsigned short* bw   = (unsigned short*)(ws + 67108864 + 33554432);
  unsigned short* at   = (unsigned short*)(ws + 67108864 + 33554432 + 2097152);

  k_cast_bf16<<<16384, 256, 0, stream>>>(x, xb, (8192 * 4096) / 8);
  k_build_bwat<<<4352, 256, 0, stream>>>(Bf, coeffs, scales, A, bw, at);
  k_gemm_prep<4096, 4096, 256><<<1024, 256, 0, stream>>>(bw, at, W, weff);
  k_gemm256<8192, 4096, 4096><<<512, 512, 0, stream>>>(xb, weff, bias, out);
}

// Round 18
// 337.209 us; speedup vs baseline: 1.1130x; 1.1130x over previous
//
#include <hip/hip_runtime.h>

typedef float f32x4 __attribute__((ext_vector_type(4)));
typedef __bf16 bf16x8 __attribute__((ext_vector_type(8)));
typedef unsigned short u16x8 __attribute__((ext_vector_type(8)));

__device__ __forceinline__ unsigned short f2bf(float f) {
  union { float f; unsigned int u; } v; v.f = f;
  unsigned int u = v.u;
  unsigned int r = (u + 0x7FFFu + ((u >> 16) & 1u)) >> 16;  // RNE
  return (unsigned short)r;
}

// ------------- cast x (f32 -> bf16), 8 elems/thread, one-shot grid -------------
__global__ __launch_bounds__(256) void k_cast_bf16(const float* __restrict__ in,
                                                   unsigned short* __restrict__ out, int n8) {
  int i = blockIdx.x * 256 + threadIdx.x;
  if (i >= n8) return;
  const f32x4* p = (const f32x4*)in;
  f32x4 a = p[2 * i], b = p[2 * i + 1];
  u16x8 o;
  o[0] = f2bf(a[0]); o[1] = f2bf(a[1]); o[2] = f2bf(a[2]); o[3] = f2bf(a[3]);
  o[4] = f2bf(b[0]); o[5] = f2bf(b[1]); o[6] = f2bf(b[2]); o[7] = f2bf(b[3]);
  ((u16x8*)out)[i] = o;
}

// ---- fused: Bw[o][e*16+r] = w[e]*Bf[e][o][r]  AND  At[d][e*16+r] = A[e][r][d] ----
__global__ void k_build_bwat(const float* __restrict__ Bf,
                             const float* __restrict__ coeffs,
                             const float* __restrict__ scales,
                             const float* __restrict__ A,
                             unsigned short* __restrict__ bw,
                             unsigned short* __restrict__ at) {
  __shared__ float tile[64][65];
  if (blockIdx.x < 4096) {
    int t = blockIdx.x * 256 + threadIdx.x;
    int o = t >> 8, k = t & 255, e = k >> 4, r = k & 15;
    float v = coeffs[e] * scales[e] * Bf[((size_t)e * 4096 + o) * 16 + r];
    bw[t] = f2bf(v);
  } else {
    int b = blockIdx.x - 4096;
    int kt = (b & 3) * 64, dt = (b >> 2) * 64;
    int tx = threadIdx.x & 63, ty = threadIdx.x >> 6;
#pragma unroll
    for (int j = 0; j < 64; j += 4)
      tile[ty + j][tx] = A[(size_t)(kt + ty + j) * 4096 + dt + tx];
    __syncthreads();
#pragma unroll
    for (int j = 0; j < 64; j += 4)
      at[(size_t)(dt + ty + j) * 256 + kt + tx] = f2bf(tile[tx][ty + j]);
  }
}

// ------------- prep GEMM (m97 structure), W_eff = Bw @ At^T + W -------------
template <int M_, int N_, int K_>
__global__ __launch_bounds__(256) void k_gemm_prep(
    const unsigned short* __restrict__ Abuf,
    const unsigned short* __restrict__ Bbuf,
    const float* __restrict__ Wadd,
    unsigned short* __restrict__ outB) {
  constexpr int NBN = N_ / 128;
  constexpr int NWG = (M_ / 128) * NBN;
  const int bid = blockIdx.x;
  const int swz = (bid & 7) * (NWG / 8) + (bid >> 3);
  const int bm = swz / NBN, bn = swz % NBN;

  __shared__ unsigned short ldsA[128 * 64];
  __shared__ unsigned short ldsB[128 * 64];

  const int t = threadIdx.x, w = t >> 6, l = t & 63;
  const int wr = w >> 1, wc = w & 1;

  f32x4 acc[4][4] = {};
  const int m0 = bm * 128, n0 = bn * 128;
  const int srow = w * 8 + (l >> 3);
  const int scol = (l & 7) * 8;
  const unsigned short* gA = Abuf + (size_t)(m0 + srow) * K_ + scol;
  const unsigned short* gB = Bbuf + (size_t)(n0 + srow) * K_ + scol;

  for (int kt = 0; kt < K_; kt += 64) {
#pragma unroll
    for (int i = 0; i < 4; ++i) {
      __builtin_amdgcn_global_load_lds(
          (__attribute__((address_space(1))) void*)(gA + (size_t)i * 32 * K_ + kt),
          (__attribute__((address_space(3))) void*)(ldsA + i * 2048 + w * 512), 16, 0, 0);
      __builtin_amdgcn_global_load_lds(
          (__attribute__((address_space(1))) void*)(gB + (size_t)i * 32 * K_ + kt),
          (__attribute__((address_space(3))) void*)(ldsB + i * 2048 + w * 512), 16, 0, 0);
    }
    __syncthreads();
#pragma unroll
    for (int kk = 0; kk < 2; ++kk) {
      const int col = kk * 32 + (l >> 4) * 8;
      const int arow = wr * 64 + (l & 15);
      const int brow = wc * 64 + (l & 15);
      bf16x8 af[4], bfv[4];
#pragma unroll
      for (int mi = 0; mi < 4; ++mi)
        af[mi] = *(const bf16x8*)&ldsA[(arow + mi * 16) * 64 + col];
#pragma unroll
      for (int ni = 0; ni < 4; ++ni)
        bfv[ni] = *(const bf16x8*)&ldsB[(brow + ni * 16) * 64 + col];
#pragma unroll
      for (int mi = 0; mi < 4; ++mi)
#pragma unroll
        for (int ni = 0; ni < 4; ++ni)
          acc[mi][ni] = __builtin_amdgcn_mfma_f32_16x16x32_bf16(
              af[mi], bfv[ni], acc[mi][ni], 0, 0, 0);
    }
    __syncthreads();
  }

  const int mrow0 = m0 + wr * 64 + (l >> 4) * 4;
  const int ncol0 = n0 + wc * 64 + (l & 15);
#pragma unroll
  for (int mi = 0; mi < 4; ++mi)
#pragma unroll
    for (int r = 0; r < 4; ++r) {
      const int m = mrow0 + mi * 16 + r;
#pragma unroll
      for (int ni = 0; ni < 4; ++ni) {
        const int n = ncol0 + ni * 16;
        outB[(size_t)m * N_ + n] = f2bf(acc[mi][ni][r] + Wadd[(size_t)m * N_ + n]);
      }
    }
}

// ===== main GEMM (R16, best measured): 256x256 tile, 16 waves (4x4, 64x64/wave),
// ===== BK=32, ring-5, R6 schedule (1 barrier / 2 K-tiles, counted vmcnt) =====
// Measured: 243-249 us, VGPR 60, SQ_LDS_BANK_CONFLICT 0, FETCH ~300 MB.
template <int M_, int N_, int K_>
__global__ __launch_bounds__(1024) void k_gemm256(
    const unsigned short* __restrict__ Abuf,
    const unsigned short* __restrict__ Bbuf,
    const float* __restrict__ bias,
    float* __restrict__ outF) {
  constexpr int NBN = N_ / 256;
  constexpr int NWG = (M_ / 256) * NBN;
  constexpr int NT = K_ / 32;
  static_assert(NWG % 8 == 0, "bijective xcd swizzle");
  static_assert(NT % 2 == 0 && NT >= 6, "pipeline depth");

  const int bid = blockIdx.x;
  const int swz = (bid & 7) * (NWG / 8) + (bid >> 3);
  const int bm = swz / NBN, bn = swz % NBN;
  const int m0 = bm * 256, n0 = bn * 256;

  __shared__ __attribute__((aligned(128))) unsigned short lds[81920];  // 160 KiB
  char* ldsb = (char*)lds;

  const int tid = threadIdx.x, w = tid >> 6, l = tid & 63;
  const int wr = w >> 2, wc = w & 3;  // 4x4 waves; per-wave out 64x64

  // staging: thread covers row w*16 + (l>>2) (A and B), linear dest lane*16;
  // global source block pre-swizzled (l&3)^((l>>3)&3) (rule #21).
  const int scol = ((l & 3) ^ ((l >> 3) & 3)) * 8;
  const unsigned short* gA = Abuf + (size_t)(m0 + w * 16 + (l >> 2)) * K_ + scol;
  const unsigned short* gB = Bbuf + (size_t)(n0 + w * 16 + (l >> 2)) * K_ + scol;
  const int dA = w * 1024;            // + buf*32768
  const int dB = 16384 + w * 1024;

  // fragment reads: row = base + (l&15); phys slot = (l>>4) ^ ((row>>1)&3)
  const int qp = ((l >> 4) ^ ((l >> 1) & 3)) << 4;
  const int raOff = (wr * 64 + (l & 15)) * 64 + qp;            // + mi*1024
  const int rbOff = 16384 + (wc * 64 + (l & 15)) * 64 + qp;    // + ni*1024

  f32x4 acc[4][4] = {};

#define STAGE_T(tt, bf)                                                               \
  do {                                                                                \
    const int bb_ = (bf) * 32768;                                                     \
    const size_t ko_ = (size_t)(tt) * 32;                                             \
    __builtin_amdgcn_global_load_lds(                                                 \
        (__attribute__((address_space(1))) void*)(gA + ko_),                          \
        (__attribute__((address_space(3))) void*)(ldsb + bb_ + dA), 16, 0, 0);        \
    __builtin_amdgcn_global_load_lds(                                                 \
        (__attribute__((address_space(1))) void*)(gB + ko_),                          \
        (__attribute__((address_space(3))) void*)(ldsb + bb_ + dB), 16, 0, 0);        \
  } while (0)

#define RD_A(mi, bf) (*(const bf16x8*)(ldsb + (bf) * 32768 + raOff + (mi) * 1024))
#define RD_B(ni, bf) (*(const bf16x8*)(ldsb + (bf) * 32768 + rbOff + (ni) * 1024))

// one K-tile: 8 ds_read_b128 -> optional stage -> 16 MFMA
#define TILE_BODY(bf, stg_t, stg_b, do_stg)                                           \
  do {                                                                                \
    bf16x8 fa[4], fb[4];                                                              \
    _Pragma("unroll") for (int i_ = 0; i_ < 4; ++i_) {                                \
      fa[i_] = RD_A(i_, bf);                                                          \
      fb[i_] = RD_B(i_, bf);                                                          \
    }                                                                                 \
    if (do_stg) STAGE_T(stg_t, stg_b);                                                \
    __builtin_amdgcn_s_setprio(1);                                                    \
    _Pragma("unroll") for (int mi_ = 0; mi_ < 4; ++mi_) {                             \
      _Pragma("unroll") for (int ni_ = 0; ni_ < 4; ++ni_)                             \
          acc[mi_][ni_] = __builtin_amdgcn_mfma_f32_16x16x32_bf16(                    \
              fa[mi_], fb[ni_], acc[mi_][ni_], 0, 0, 0);                              \
    }                                                                                 \
    __builtin_amdgcn_s_setprio(0);                                                    \
  } while (0)

  // prologue: stage tiles 0,1,2 into bufs 0,1,2 (6 instr in flight)
  STAGE_T(0, 0); STAGE_T(1, 1); STAGE_T(2, 2);

  int bT = 0;  // buf index of tile tt (tt % 5)
  for (int tt = 0; tt < NT; tt += 2) {
    const int b0 = bT;
    const int b1 = (bT + 1 >= 5) ? bT + 1 - 5 : bT + 1;
    const int s3 = (bT + 3 >= 5) ? bT + 3 - 5 : bT + 3;
    const int s4 = (bT + 4 >= 5) ? bT + 4 - 5 : bT + 4;
    const bool st3 = (tt + 3) < NT, st4 = (tt + 4) < NT;

    // drain tiles tt, tt+1 (issued a full iteration ago); keep tt+2 in flight
    if (tt + 2 < NT) asm volatile("s_waitcnt vmcnt(2)" ::: "memory");
    else             asm volatile("s_waitcnt vmcnt(0)" ::: "memory");
    __builtin_amdgcn_s_barrier();
    __builtin_amdgcn_sched_barrier(0);

    TILE_BODY(b0, tt + 3, s3, st3);
    TILE_BODY(b1, tt + 4, s4, st4);

    bT += 2; if (bT >= 5) bT -= 5;
  }
#undef STAGE_T
#undef RD_A
#undef RD_B
#undef TILE_BODY

  // epilogue: C/D layout col = lane&15, row = (lane>>4)*4 + reg
#pragma unroll
  for (int ni = 0; ni < 4; ++ni) {
    const int n = n0 + wc * 64 + ni * 16 + (l & 15);
    const float bv2 = bias[n];
#pragma unroll
    for (int mi = 0; mi < 4; ++mi) {
      const int m = m0 + wr * 64 + mi * 16 + (l >> 4) * 4;
#pragma unroll
      for (int r = 0; r < 4; ++r)
        outF[(size_t)(m + r) * N_ + n] = acc[mi][ni][r] + bv2;
    }
  }
}

extern "C" void kernel_launch(void* const* d_in, const int* in_sizes, int n_in,
                              void* d_out, int out_size, void* d_ws, size_t ws_size,
                              hipStream_t stream) {
  const float* x      = (const float*)d_in[0];
  const float* W      = (const float*)d_in[1];
  const float* bias   = (const float*)d_in[2];
  const float* A      = (const float*)d_in[3];
  const float* Bf     = (const float*)d_in[4];
  const float* coeffs = (const float*)d_in[5];
  const float* scales = (const float*)d_in[6];
  float* out = (float*)d_out;

  char* ws = (char*)d_ws;
  unsigned short* xb   = (unsigned short*)(ws);
  unsigned short* weff = (unsigned short*)(ws + 67108864);
  unsigned short* bw   = (unsigned short*)(ws + 67108864 + 33554432);
  unsigned short* at   = (unsigned short*)(ws + 67108864 + 33554432 + 2097152);

  k_cast_bf16<<<16384, 256, 0, stream>>>(x, xb, (8192 * 4096) / 8);
  k_build_bwat<<<4352, 256, 0, stream>>>(Bf, coeffs, scales, A, bw, at);
  k_gemm_prep<4096, 4096, 256><<<1024, 256, 0, stream>>>(bw, at, W, weff);
  k_gemm256<8192, 4096, 4096><<<512, 1024, 0, stream>>>(xb, weff, bias, out);
}